// Round 12
// baseline (524.849 us; speedup 1.0000x reference)
//
#include <hip/hip_runtime.h>
#include <hip/hip_bf16.h>

// KMeans predict: ids = argmin_k ||c_k||^2 - 2 x.c_k    (N=500000, D=64, K=1024)
// Pass 0: fp64 ||c||^2 table + f16(hi) center table (128 KB, top of workspace;
//         L2-resident). The f16 cvt is identical to the old LDS-staging cvt,
//         so pass1 scores are bit-identical to the verified R11 kernel.
// Pass 1: 32x32x16 f16 MFMA, A = centers f16 DIRECT FROM GLOBAL (L2), B =
//         points f16-hi (regs). NO LDS STAGING, NO K-LOOP BARRIERS (one
//         prologue barrier for the 4 KB permuted -0.5||c||^2 table). 4 MFMAs
//         per tile. Ledger: pass1 time tracks MFMA count (6.9us/MFMA) and
//         barrier count (~4.5us/pair); occupancy/ILP/op-shaping all neutral.
//         This round removes ALL remaining K-loop sync.
// Pass 2: fp64-exact wave-per-point rescan (grid 3072), MARGIN 1.5e-2
//         (verified absmax 0 in R10/R11).

#define N_PTS 500000
#define DIM   64
#define K_CENT 1024
#define MARGIN 1.5e-2f   // covers f16-hi product noise (~5.4e-3 rms) + pack quant

typedef _Float16 half8   __attribute__((ext_vector_type(8)));
typedef float    floatx16 __attribute__((ext_vector_type(16)));

// ---------------------------------------------------------------- pass 0 ----
// fp64 ||c||^2 table + f16 center copy, 1024 centers, one thread each.
__global__ void kmeans_m2pre(const float* __restrict__ centers,
                             double* __restrict__ m2d,
                             _Float16* __restrict__ cf16)
{
    const int c = blockIdx.x * 256 + threadIdx.x;
    if (c >= K_CENT) return;
    const float4* crow = (const float4*)(centers + (size_t)c * DIM);
    _Float16* frow = cf16 + (size_t)c * DIM;
    double s = 0.0;
    #pragma unroll
    for (int g = 0; g < 8; ++g) {
        float4 f0 = crow[2 * g], f1 = crow[2 * g + 1];
        double a = f0.x, b = f0.y, cc = f0.z, d = f0.w;
        double e = f1.x, f = f1.y, gg = f1.z, hh = f1.w;
        s += a * a + b * b + cc * cc + d * d + e * e + f * f + gg * gg + hh * hh;
        float v[8] = {f0.x, f0.y, f0.z, f0.w, f1.x, f1.y, f1.z, f1.w};
        half8 hi;
        #pragma unroll
        for (int j = 0; j < 8; ++j) hi[j] = (_Float16)v[j];   // same cvt as staging
        *(half8*)(frow + g * 8) = hi;
    }
    m2d[c] = s;
}

// ---------------------------------------------------------------- pass 1 ----
// 512 threads = 8 waves; each wave owns 32 points (one 32-col C tile).
// A-fragments stream straight from the 128 KB global f16 table (L2-hit).
// negm2p holds -0.5||c||^2 fp32 permuted into MFMA C-fragment order
// [tile][h][reg] so each tile's acc inits with one broadcast 64 B LDS read.
__launch_bounds__(512, 4)
__global__ void kmeans_pass1(const float* __restrict__ x,
                             const _Float16* __restrict__ cf16,
                             const double* __restrict__ m2d,
                             int* __restrict__ out,
                             int* __restrict__ counter,
                             int* __restrict__ ulist,
                             int capacity)
{
    __shared__ __align__(64) float negm2p[K_CENT];      // 4 KB only

    const int tid  = threadIdx.x;
    const int lane = tid & 63;
    const int wave = tid >> 6;
    const int col  = lane & 31;      // point within wave's 32
    const int h    = lane >> 5;      // k-half selector (8 of 16 per chunk)

    const int p  = blockIdx.x * 256 + wave * 32 + col;
    const int pc = p > N_PTS - 1 ? N_PTS - 1 : p;       // tail clamp (dup)

    // ---- B fragments (points), hi only: B[k = c*16 + h*8 + j][n = col] ----
    half8 bh[4];
    {
        const float* xr = x + (size_t)pc * DIM + h * 8;
        #pragma unroll
        for (int c = 0; c < 4; ++c) {
            float4 f0 = *(const float4*)(xr + c * 16);
            float4 f1 = *(const float4*)(xr + c * 16 + 4);
            float v[8] = {f0.x, f0.y, f0.z, f0.w, f1.x, f1.y, f1.z, f1.w};
            half8 hi;
            #pragma unroll
            for (int j = 0; j < 8; ++j) hi[j] = (_Float16)v[j];
            bh[c] = hi;
        }
    }

    // ---- prologue: permuted C-init table, then the ONLY barrier ----
    // center idx = ct*32 + r lives at [ct*32 + hp*16 + reg],
    // hp=(r>>2)&1, reg=(r&3)|((r>>3)<<2)  (inverse: row=(reg&3)+8*(reg>>2)+4h)
    #pragma unroll
    for (int i = 0; i < 2; ++i) {
        const int idx = tid + i * 512;
        const int r = idx & 31, ct = idx >> 5;
        const int hp = (r >> 2) & 1, reg = (r & 3) | ((r >> 3) << 2);
        negm2p[ct * 32 + hp * 16 + reg] = -0.5f * (float)m2d[idx];
    }
    __syncthreads();

    float m1 = -3.0e38f, m2 = -3.0e38f;
    int   ctb = 0;

    // ---- K-loop: 32 tiles, ZERO barriers, waves fully independent ----
    #pragma unroll 2
    for (int ct = 0; ct < 32; ++ct) {
        // A fragments: A[m = ct*32+col][k = c*16 + h*8 + j], straight from L2
        const _Float16* ap = cf16 + ((size_t)(ct * 32 + col)) * DIM + h * 8;
        half8 a0 = *(const half8*)(ap);
        half8 a1 = *(const half8*)(ap + 16);
        half8 a2 = *(const half8*)(ap + 32);
        half8 a3 = *(const half8*)(ap + 48);

        // C-init: one broadcast 64B LDS load, already in fragment order
        floatx16 acc = *(const floatx16*)&negm2p[ct * 32 + h * 16];
        acc = __builtin_amdgcn_mfma_f32_32x32x16_f16(a0, bh[0], acc, 0, 0, 0);
        acc = __builtin_amdgcn_mfma_f32_32x32x16_f16(a1, bh[1], acc, 0, 0, 0);
        acc = __builtin_amdgcn_mfma_f32_32x32x16_f16(a2, bh[2], acc, 0, 0, 0);
        acc = __builtin_amdgcn_mfma_f32_32x32x16_f16(a3, bh[3], acc, 0, 0, 0);

        // ---- top-2 fold: max/min per element, reg-id in low 4 bits ----
        // invariant m1 >= m2; m2' = max(m2, min(m1,k)); m1' = max(m1,k)
        const float pre = m1;
        #pragma unroll
        for (int i = 0; i < 16; ++i) {
            unsigned u = (__float_as_uint(acc[i]) & 0xFFFFFFF0u) | (unsigned)i;
            float k = __uint_as_float(u);
            m2 = fmaxf(m2, fminf(m1, k));
            m1 = fmaxf(m1, k);
        }
        ctb = (m1 > pre) ? ct : ctb;
    }

    // ---- epilogue: recover center id, merge the two k-halves, write ----
    {
        unsigned u = __float_as_uint(m1);
        int reg = (int)(u & 15u);
        int row = (reg & 3) + 8 * (reg >> 2) + 4 * h;
        int cid = ctb * 32 + row;

        float o1 = __shfl_xor(m1, 32);
        float o2 = __shfl_xor(m2, 32);
        int  ocid = __shfl_xor(cid, 32);
        float nm2 = fmaxf(fmaxf(m2, o2), fminf(m1, o1));
        bool take = o1 > m1;
        float nm1 = take ? o1 : m1;
        int  ncid = take ? ocid : cid;

        if (h == 0 && p < N_PTS) {
            out[p] = ncid;
            if (nm1 - nm2 < MARGIN) {                    // too close -> fp64
                int slot = atomicAdd(counter, 1);
                if (slot < capacity) ulist[slot] = p;
            }
        }
    }
}

// ---------------------------------------------------------------- pass 2 ----
// fp64-exact, ONE WAVE PER POINT. Lane q=lane&15 owns one float4 of the dim
// axis; rg=lane>>4 one of 4 rows per load -> each wave-load is a coalesced
// 1 KB read of 4 center rows. dot reduced by shfl_xor butterfly over q bits.
// ||c||^2 comes from the fp64 precompute table.
__launch_bounds__(256)
__global__ void kmeans_pass2(const float* __restrict__ x,
                             const float* __restrict__ centers,
                             const double* __restrict__ m2d,
                             int* __restrict__ out,
                             const int* __restrict__ counter,
                             const int* __restrict__ ulist,
                             int capacity)
{
    int count = *counter;
    if (count > capacity) count = capacity;

    const int tid   = threadIdx.x;
    const int lane  = tid & 63;
    const int q     = lane & 15;                 // float4 chunk of the row
    const int rg    = lane >> 4;                 // row-in-group 0..3
    const int waveg = (blockIdx.x * 256 + tid) >> 6;   // global wave id
    const int nwave = (gridDim.x * 256) >> 6;

    for (int u = waveg; u < count; u += nwave) {
        const int p = ulist[u];
        float4 xv = *(const float4*)(x + (size_t)p * DIM + q * 4);
        const double x0 = xv.x, x1 = xv.y, x2 = xv.z, x3 = xv.w;

        double bv = 1.0e300; int bi = 0;
        #pragma unroll 4
        for (int g = 0; g < 256; ++g) {
            const int row = g * 4 + rg;
            float4 cv = *(const float4*)(centers + (size_t)row * DIM + q * 4);
            double dot = (double)cv.x * x0 + (double)cv.y * x1
                       + (double)cv.z * x2 + (double)cv.w * x3;
            #pragma unroll
            for (int m = 1; m <= 8; m <<= 1)
                dot += __shfl_xor(dot, m);       // all 16 q-lanes get the total
            double s = m2d[row] - 2.0 * dot;
            if (s < bv || (s == bv && row < bi)) { bv = s; bi = row; }
        }
        #pragma unroll
        for (int m = 16; m <= 32; m <<= 1) {     // merge the 4 rg groups
            double ov = __shfl_xor(bv, m);
            int    oi = __shfl_xor(bi, m);
            if (ov < bv || (ov == bv && oi < bi)) { bv = ov; bi = oi; }
        }
        if (lane == 0) out[p] = bi;
    }
}

extern "C" void kernel_launch(void* const* d_in, const int* in_sizes, int n_in,
                              void* d_out, int out_size, void* d_ws, size_t ws_size,
                              hipStream_t stream)
{
    const float* x       = (const float*)d_in[0];
    const float* centers = (const float*)d_in[1];
    int*    out     = (int*)d_out;
    int*    counter = (int*)d_ws;
    double* m2d     = (double*)((char*)d_ws + 1024);
    int*    ulist   = (int*)((char*)d_ws + 9216);

    // f16 center table parked at the TOP of workspace (128 KB, 256 B aligned);
    // ulist keeps its proven 9216 offset and simply ends below the table.
    const size_t CF16_BYTES = (size_t)K_CENT * DIM * sizeof(_Float16);  // 131072
    size_t cfoff = (ws_size > CF16_BYTES + 9216 + 64)
                 ? ((ws_size - CF16_BYTES) & ~(size_t)255) : 9216;
    _Float16* cf16 = (_Float16*)((char*)d_ws + cfoff);
    int capacity = (int)((cfoff > 9216 ? cfoff - 9216 : 0) / sizeof(int));
    if (capacity > N_PTS) capacity = N_PTS;

    hipMemsetAsync(d_ws, 0, 64, stream);
    kmeans_m2pre<<<4, 256, 0, stream>>>(centers, m2d, cf16);
    dim3 g1((N_PTS + 255) / 256);     // 1954 blocks x 512 threads, 256 pts each
    kmeans_pass1<<<g1, 512, 0, stream>>>(x, cf16, m2d, out, counter, ulist, capacity);
    kmeans_pass2<<<3072, 256, 0, stream>>>(x, centers, m2d, out, counter, ulist, capacity);
}